// Round 9
// baseline (1565.772 us; speedup 1.0000x reference)
//
#include <hip/hip_runtime.h>
#include <hip/hip_bf16.h>
#include <stdint.h>

// Problem dims (fixed by the reference setup)
#define BDIM 8192      // rows of x
#define CDIM 10000     // class means
#define CPAD 10240     // 40 * 256
#define FDIM 2048      // feature dim (K)

#define BM 256
#define BN 256
#define BKB 64                  // K-chunk = 64 i8 elems = 64 bytes per row
#define NT (FDIM / BKB)         // 32 K-chunks
#define NI (NT / 2)             // 16 iterations (2 K-chunks each)
#define TM (BDIM / BM)          // 32
#define TN (CPAD / BN)          // 40
#define NWG (TM * TN)           // 1280, multiple of 8

#define HT_BYTES   8192         // one half-tile region (128 rows x 64 B)
#define DBUF_BYTES 32768        // A0|A1|B0|B1 (one K-chunk, both mats)
#define EPI_WAVE_BYTES 4352     // 16 rows x 68 f32 (epilogue transpose chunk)
#define LDS_BYTES  65536        // 64 KB exactly -> 2 blocks/CU guaranteed

// int8 quantization: step q = QS, symmetric [-127,127]
#define QSF   (6.5f / 127.0f)
#define INVQ  (127.0f / 6.5f)
#define TSC   (2.0f * QSF * QSF)

typedef __attribute__((ext_vector_type(4))) int   i32x4;
typedef __attribute__((ext_vector_type(4))) float f32x4;

#define AS1 __attribute__((address_space(1)))
#define AS3 __attribute__((address_space(3)))

// ---------------------------------------------------------------------------
// Prep (fused): f32 rows -> i8 rows (RNE quant, clamp +-127) + per-row sum of
// squares in f32 (exact). Blocks [0,BDIM) = x; [BDIM, BDIM+CPAD) = means.
// ---------------------------------------------------------------------------
__global__ __launch_bounds__(256) void convert_rows(
    const float* __restrict__ xsrc, const float* __restrict__ msrc,
    signed char* __restrict__ Xq, signed char* __restrict__ Mq,
    float* __restrict__ xsq, float* __restrict__ msq)
{
    const int b = blockIdx.x;
    const int tid = threadIdx.x;

    const float* src;
    signed char* drow;
    float* sq;
    int row;
    if (b < BDIM) {
        row = b; src = xsrc + (size_t)row * FDIM;
        drow = Xq + (size_t)row * FDIM; sq = xsq + row;
    } else {
        row = b - BDIM;
        drow = Mq + (size_t)row * FDIM; sq = msq + row;
        if (row >= CDIM) {
            ((uint2*)drow)[tid] = make_uint2(0, 0);
            if (tid == 0) *sq = 0.0f;
            return;
        }
        src = msrc + (size_t)row * FDIM;
    }

    const float4* s = (const float4*)src;
    float4 v0 = s[tid * 2 + 0];
    float4 v1 = s[tid * 2 + 1];

    float f[8] = {v0.x, v0.y, v0.z, v0.w, v1.x, v1.y, v1.z, v1.w};
    float ssum = 0.0f;
    union { unsigned char u[8]; uint2 v; } pk;
#pragma unroll
    for (int j = 0; j < 8; ++j) {
        ssum += f[j] * f[j];
        int q = (int)__builtin_rintf(f[j] * INVQ);
        q = q > 127 ? 127 : (q < -127 ? -127 : q);
        pk.u[j] = (unsigned char)(q & 0xff);
    }
    ((uint2*)drow)[tid] = pk.v;

#pragma unroll
    for (int off = 32; off > 0; off >>= 1)
        ssum += __shfl_down(ssum, off, 64);
    __shared__ float red[4];
    if ((tid & 63) == 0) red[tid >> 6] = ssum;
    __syncthreads();
    if (tid == 0) *sq = red[0] + red[1] + red[2] + red[3];
}

// ---------------------------------------------------------------------------
// 256x256 int8 GEMM (mfma_i32_16x16x64_i8), 8-phase counted-vmcnt schedule,
// 64 KB LDS total -> 2 blocks/CU: cross-block overlap decouples the
// lockstep {stage, ds_read, barrier} phases from the MFMA pipe.
// out[i][j] = 2*QS^2*acc_int - xsq[i] - msq[j]
// ---------------------------------------------------------------------------
#define MIDSYNC() do { \
    __builtin_amdgcn_s_barrier(); \
    asm volatile("s_waitcnt lgkmcnt(0)" ::: "memory"); \
    __builtin_amdgcn_sched_barrier(0); \
} while (0)

#define ENDBAR() do { \
    __builtin_amdgcn_s_barrier(); \
    __builtin_amdgcn_sched_barrier(0); \
} while (0)

// one quadrant-phase: 8 MFMA (K=64 per chunk)
#define QUAD(MH, BV, NH) do { \
    __builtin_amdgcn_s_setprio(1); \
    _Pragma("unroll") \
    for (int f = 0; f < 4; ++f) \
      _Pragma("unroll") \
      for (int f2 = 0; f2 < 2; ++f2) \
        acc[(MH)*4+f][(NH)*2+f2] = __builtin_amdgcn_mfma_i32_16x16x64_i8( \
            av[f], BV[f2], acc[(MH)*4+f][(NH)*2+f2], 0, 0, 0); \
    __builtin_amdgcn_s_setprio(0); \
} while (0)

__global__ __launch_bounds__(512, 4) void nscm_gemm(
    const signed char* __restrict__ Xq, const signed char* __restrict__ Mq,
    const float* __restrict__ xsq, const float* __restrict__ msq,
    float* __restrict__ out)
{
    extern __shared__ char lds[];

    const int tid  = threadIdx.x;
    const int lane = tid & 63;
    const int wave = tid >> 6;       // 0..7
    const int wr = wave >> 2;        // 0..1  (M half)
    const int wc = wave & 3;         // 0..3  (N quarter)
    const int fr = lane & 15;
    const int kq = lane >> 4;        // 0..3

    // T1 + 2D clustering: xcd slab = 4 rows x 40 cols, five 4x8 sub-rects
    const int bid = blockIdx.x;
    const int xcd = bid & 7;
    const int c   = bid >> 3;            // 0..159 within XCD slab
    const int sub = c >> 5;              // 0..4   (column group of 8)
    const int tile_m = xcd * 4 + (c & 3);
    const int tile_n = sub * 8 + ((c >> 2) & 7);
    const int row0 = tile_m * BM;
    const int col0 = tile_n * BN;

    // staging: thread tid stages LDS row w=tid>>2, slot tid&3 (16 B each).
    // 2-way-free swizzle for 64-B rows: LDS(w,s) holds global col16
    // c = s ^ ((w>>1)&3)  -> source pre-swizzle:
    const int sw  = tid >> 2;                              // LDS row staged
    const int sce = (((tid & 3) ^ ((tid >> 3) & 3))) * 16; // src col bytes
    const int rslot = (kq ^ ((fr >> 1) & 3)) * 16;         // read-side slot

    i32x4 acc[8][4] = {};
    i32x4 av[4], bv0[2], bv1[2];

    // stage one A half-tile (h: rows with bit6==h) of K-chunk kt into buf
    auto stageA = [&](int kt, int buf, int h) {
        const int grow = row0 + (sw >> 6) * 128 + h * 64 + (sw & 63);
        const signed char* src = Xq + (size_t)grow * FDIM + kt * BKB + sce;
        char* dst = lds + buf * DBUF_BYTES + h * HT_BYTES + wave * 1024;
        __builtin_amdgcn_global_load_lds((const AS1 void*)src,
                                         (AS3 void*)dst, 16, 0, 0);
    };
    // stage one B half-tile (h: rows with bit5==h)
    auto stageB = [&](int kt, int buf, int h) {
        const int grow = col0 + (sw >> 5) * 64 + h * 32 + (sw & 31);
        const signed char* src = Mq + (size_t)grow * FDIM + kt * BKB + sce;
        char* dst = lds + buf * DBUF_BYTES + 16384 + h * HT_BYTES + wave * 1024;
        __builtin_amdgcn_global_load_lds((const AS1 void*)src,
                                         (AS3 void*)dst, 16, 0, 0);
    };

    auto loadA = [&](int buf, int mh) {
        const char* base = lds + buf * DBUF_BYTES + mh * HT_BYTES;
#pragma unroll
        for (int f = 0; f < 4; ++f) {
            const int w = wr * 64 + f * 16 + fr;
            av[f] = *(const i32x4*)(base + w * 64 + rslot);
        }
    };
    auto loadB = [&](int buf, int nh, i32x4 (&bv)[2]) {
        const char* base = lds + buf * DBUF_BYTES + 16384 + nh * HT_BYTES;
#pragma unroll
        for (int f = 0; f < 2; ++f) {
            const int w = wc * 32 + f * 16 + fr;
            bv[f] = *(const i32x4*)(base + w * 64 + rslot);
        }
    };

    // prologue: 7 half-tiles (buf0 chunk0 complete + 3/4 of buf1 chunk1)
    stageA(0, 0, 0); stageB(0, 0, 0); stageB(0, 0, 1); stageA(0, 0, 1);
    stageA(1, 1, 0); stageB(1, 1, 0); stageB(1, 1, 1);
    asm volatile("s_waitcnt vmcnt(3)" ::: "memory");   // buf0 chunk0 landed
    __builtin_amdgcn_s_barrier();
    __builtin_amdgcn_sched_barrier(0);

    for (int t = 0; t < NI; ++t) {
        const int kO1 = 2 * t + 1;                 // odd chunk (buf1), valid
        const int kE2 = (2 * t + 2) & (NT - 1);    // next even (dummy-wraps at end)
        const int kO3 = (2 * t + 3) & (NT - 1);    // next odd

        // ph1: reads A(mh0),B(nh0) of buf0; stage Ah1(buf1, chunk 2t+1)
        loadA(0, 0); loadB(0, 0, bv0);
        stageA(kO1, 1, 1);
        MIDSYNC();
        QUAD(0, bv0, 0);
        ENDBAR();

        // ph2: reads B(nh1) of buf0; stage Ah0(buf0, 2t+2)
        loadB(0, 1, bv1);
        stageA(kE2, 0, 0);
        MIDSYNC();
        QUAD(0, bv1, 1);
        ENDBAR();

        // ph3: reads A(mh1) of buf0; stage Bh0(buf0, 2t+2)
        loadA(0, 1);
        stageB(kE2, 0, 0);
        MIDSYNC();
        QUAD(1, bv0, 0);
        ENDBAR();

        // ph4: stage Bh1(buf0, 2t+2); counted vmcnt (3 half-tiles in flight)
        stageB(kE2, 0, 1);
        asm volatile("s_waitcnt vmcnt(3)" ::: "memory");
        MIDSYNC();
        QUAD(1, bv1, 1);
        ENDBAR();

        // ph5: reads A(mh0),B(nh0) of buf1; stage Ah1(buf0, 2t+2)
        loadA(1, 0); loadB(1, 0, bv0);
        stageA(kE2, 0, 1);
        MIDSYNC();
        QUAD(0, bv0, 0);
        ENDBAR();

        // ph6: reads B(nh1) of buf1; stage Ah0(buf1, 2t+3)
        loadB(1, 1, bv1);
        stageA(kO3, 1, 0);
        MIDSYNC();
        QUAD(0, bv1, 1);
        ENDBAR();

        // ph7: reads A(mh1) of buf1; stage Bh0(buf1, 2t+3)
        loadA(1, 1);
        stageB(kO3, 1, 0);
        MIDSYNC();
        QUAD(1, bv0, 0);
        ENDBAR();

        // ph8: stage Bh1(buf1, 2t+3); counted vmcnt
        stageB(kO3, 1, 1);
        asm volatile("s_waitcnt vmcnt(3)" ::: "memory");
        MIDSYNC();
        QUAD(1, bv1, 1);
        ENDBAR();
    }

    // drain dummy stages (they write LDS) and sync before epilogue reuses LDS
    asm volatile("s_waitcnt vmcnt(0)" ::: "memory");
    __builtin_amdgcn_s_barrier();
    __builtin_amdgcn_sched_barrier(0);

    // ---- epilogue: per-wave LDS transpose (16-row passes) -> float4 nt stores
    // out[i][j] = TSC*acc - xsq[i] - msq[j]
    float* wtile = (float*)(lds + wave * EPI_WAVE_BYTES);  // [16][68] f32
    const int rr = lane >> 4;              // 0..3 (row within 4-row group)
    const int cq = lane & 15;              // col-quad index
    const int gc = col0 + wc * 64 + cq * 4;
    float ms0 = 0.f, ms1 = 0.f, ms2 = 0.f, ms3 = 0.f;
    if (gc < CDIM) {
        ms0 = msq[gc]; ms1 = msq[gc + 1]; ms2 = msq[gc + 2]; ms3 = msq[gc + 3];
    }

#pragma unroll
    for (int p = 0; p < 8; ++p) {          // rows [p*16, p*16+16) of 128
        // scatter one fm-subtile into the wave's [16][68] chunk
#pragma unroll
        for (int fn = 0; fn < 4; ++fn) {
            const int lr = kq * 4;
            const int lc = fn * 16 + fr;
#pragma unroll
            for (int r = 0; r < 4; ++r)
                wtile[(lr + r) * 68 + lc] = (float)acc[p][fn][r];
        }
        asm volatile("s_waitcnt lgkmcnt(0)" ::: "memory");
        __builtin_amdgcn_sched_barrier(0);

        if (gc < CDIM) {
#pragma unroll
            for (int i = 0; i < 4; ++i) {
                const int row = i * 4 + rr;                 // [0,16)
                f32x4 v = *(const f32x4*)&wtile[row * 68 + cq * 4];
                const int gr = row0 + wr * 128 + p * 16 + row;
                const float xsv = xsq[gr];
                f32x4 o;
                o[0] = TSC * v[0] - xsv - ms0;
                o[1] = TSC * v[1] - xsv - ms1;
                o[2] = TSC * v[2] - xsv - ms2;
                o[3] = TSC * v[3] - xsv - ms3;
                __builtin_nontemporal_store(
                    o, (f32x4*)(out + (size_t)gr * CDIM + gc));
            }
        }
        // wave-local reuse of wtile in next pass: ensure reads retired
        asm volatile("s_waitcnt lgkmcnt(0)" ::: "memory");
        __builtin_amdgcn_sched_barrier(0);
    }
}

// ---------------------------------------------------------------------------
extern "C" void kernel_launch(void* const* d_in, const int* in_sizes, int n_in,
                              void* d_out, int out_size, void* d_ws, size_t ws_size,
                              hipStream_t stream) {
    const float* x     = (const float*)d_in[0];   // [8192, 2048]
    const float* means = (const float*)d_in[1];   // [10000, 2048]
    float* out = (float*)d_out;                   // [8192, 10000]

    char* ws = (char*)d_ws;
    signed char* Xq = (signed char*)ws;                            // 8192*2048 i8
    signed char* Mq = (signed char*)(ws + (size_t)BDIM * FDIM);    // 10240*2048 i8
    float* xsq = (float*)(ws + (size_t)BDIM * FDIM + (size_t)CPAD * FDIM);
    float* msq = xsq + BDIM;

    (void)hipFuncSetAttribute((const void*)nscm_gemm,
                              hipFuncAttributeMaxDynamicSharedMemorySize,
                              LDS_BYTES);

    convert_rows<<<BDIM + CPAD, 256, 0, stream>>>(x, means, Xq, Mq, xsq, msq);

    nscm_gemm<<<NWG, 512, LDS_BYTES, stream>>>(Xq, Mq, xsq, msq, out);
}

// Round 10
// 213.885 us; speedup vs baseline: 7.3206x; 7.3206x over previous
//
#include <hip/hip_runtime.h>
#include <hip/hip_bf16.h>
#include <stdint.h>

// Problem dims (fixed by the reference setup)
#define BDIM 8192      // rows of x
#define CDIM 10000     // class means
#define CPAD 10240     // 40 * 256
#define FDIM 2048      // feature dim (K)

#define BM 256
#define BN 256
#define BKB 64                  // K-chunk = 64 i8 elems = 64 bytes per row
#define NT (FDIM / BKB)         // 32 K-chunks
#define NI (NT / 2)             // 16 iterations (2 K-chunks each)
#define TM (BDIM / BM)          // 32
#define TN (CPAD / BN)          // 40
#define NWG (TM * TN)           // 1280, multiple of 8

#define HT_BYTES   8192         // one half-tile region (128 rows x 64 B)
#define DBUF_BYTES 32768        // A0|A1|B0|B1 (one K-chunk, both mats)
#define EPI_WAVE_BYTES 4352     // 16 rows x 68 f32 (epilogue transpose chunk)
#define LDS_BYTES  65536

// int8 quantization: step q = QS, symmetric [-127,127]
#define QSF   (6.5f / 127.0f)
#define INVQ  (127.0f / 6.5f)
#define TSC   (2.0f * QSF * QSF)

typedef __attribute__((ext_vector_type(4))) int   i32x4;
typedef __attribute__((ext_vector_type(4))) float f32x4;

#define AS1 __attribute__((address_space(1)))
#define AS3 __attribute__((address_space(3)))

// ---------------------------------------------------------------------------
// Prep (fused): f32 rows -> i8 rows (RNE quant, clamp +-127) + per-row sum of
// squares in f32 (exact). Blocks [0,BDIM) = x; [BDIM, BDIM+CPAD) = means.
// ---------------------------------------------------------------------------
__global__ __launch_bounds__(256) void convert_rows(
    const float* __restrict__ xsrc, const float* __restrict__ msrc,
    signed char* __restrict__ Xq, signed char* __restrict__ Mq,
    float* __restrict__ xsq, float* __restrict__ msq)
{
    const int b = blockIdx.x;
    const int tid = threadIdx.x;

    const float* src;
    signed char* drow;
    float* sq;
    int row;
    if (b < BDIM) {
        row = b; src = xsrc + (size_t)row * FDIM;
        drow = Xq + (size_t)row * FDIM; sq = xsq + row;
    } else {
        row = b - BDIM;
        drow = Mq + (size_t)row * FDIM; sq = msq + row;
        if (row >= CDIM) {
            ((uint2*)drow)[tid] = make_uint2(0, 0);
            if (tid == 0) *sq = 0.0f;
            return;
        }
        src = msrc + (size_t)row * FDIM;
    }

    const float4* s = (const float4*)src;
    float4 v0 = s[tid * 2 + 0];
    float4 v1 = s[tid * 2 + 1];

    float f[8] = {v0.x, v0.y, v0.z, v0.w, v1.x, v1.y, v1.z, v1.w};
    float ssum = 0.0f;
    union { unsigned char u[8]; uint2 v; } pk;
#pragma unroll
    for (int j = 0; j < 8; ++j) {
        ssum += f[j] * f[j];
        int q = (int)__builtin_rintf(f[j] * INVQ);
        q = q > 127 ? 127 : (q < -127 ? -127 : q);
        pk.u[j] = (unsigned char)(q & 0xff);
    }
    ((uint2*)drow)[tid] = pk.v;

#pragma unroll
    for (int off = 32; off > 0; off >>= 1)
        ssum += __shfl_down(ssum, off, 64);
    __shared__ float red[4];
    if ((tid & 63) == 0) red[tid >> 6] = ssum;
    __syncthreads();
    if (tid == 0) *sq = red[0] + red[1] + red[2] + red[3];
}

// ---------------------------------------------------------------------------
// 256x256 int8 GEMM (mfma_i32_16x16x64_i8), 8-phase counted-vmcnt schedule
// with ONE-PHASE ds_read READ-AHEAD: each phase issues the next phase's
// fragment reads (into the alternate register set) right after its MIDSYNC,
// so ds_read latency hides under the current phase's MFMA cluster.
// RAW: every early read's source half-tile is retired by the existing
// vmcnt(3)@ph4/ph8.  WAR: every region's next re-stage is >= +2 phases
// after its early read; every register set is dead >= 1 phase before reuse.
// out[i][j] = 2*QS^2*acc_int - xsq[i] - msq[j]
// ---------------------------------------------------------------------------
#define MIDSYNC() do { \
    __builtin_amdgcn_s_barrier(); \
    asm volatile("s_waitcnt lgkmcnt(0)" ::: "memory"); \
    __builtin_amdgcn_sched_barrier(0); \
} while (0)

#define ENDBAR() do { \
    __builtin_amdgcn_s_barrier(); \
    __builtin_amdgcn_sched_barrier(0); \
} while (0)

#define SCHEDBAR() __builtin_amdgcn_sched_barrier(0)

// one quadrant-phase: 8 MFMA (K=64 per chunk), explicit A/B register sets
#define QUAD(MH, AV, BV, NH) do { \
    __builtin_amdgcn_s_setprio(1); \
    _Pragma("unroll") \
    for (int f = 0; f < 4; ++f) \
      _Pragma("unroll") \
      for (int f2 = 0; f2 < 2; ++f2) \
        acc[(MH)*4+f][(NH)*2+f2] = __builtin_amdgcn_mfma_i32_16x16x64_i8( \
            AV[f], BV[f2], acc[(MH)*4+f][(NH)*2+f2], 0, 0, 0); \
    __builtin_amdgcn_s_setprio(0); \
} while (0)

__global__ __launch_bounds__(512, 2) void nscm_gemm(
    const signed char* __restrict__ Xq, const signed char* __restrict__ Mq,
    const float* __restrict__ xsq, const float* __restrict__ msq,
    float* __restrict__ out)
{
    extern __shared__ char lds[];

    const int tid  = threadIdx.x;
    const int lane = tid & 63;
    const int wave = tid >> 6;       // 0..7
    const int wr = wave >> 2;        // 0..1  (M half)
    const int wc = wave & 3;         // 0..3  (N quarter)
    const int fr = lane & 15;
    const int kq = lane >> 4;        // 0..3

    // T1 + 2D clustering: xcd slab = 4 rows x 40 cols, five 4x8 sub-rects
    const int bid = blockIdx.x;
    const int xcd = bid & 7;
    const int c   = bid >> 3;            // 0..159 within XCD slab
    const int sub = c >> 5;              // 0..4   (column group of 8)
    const int tile_m = xcd * 4 + (c & 3);
    const int tile_n = sub * 8 + ((c >> 2) & 7);
    const int row0 = tile_m * BM;
    const int col0 = tile_n * BN;

    // staging: thread tid stages LDS row w=tid>>2, slot tid&3 (16 B each).
    // 2-way-free swizzle for 64-B rows: LDS(w,s) holds global col16
    // c = s ^ ((w>>1)&3)  -> source pre-swizzle:
    const int sw  = tid >> 2;                              // LDS row staged
    const int sce = (((tid & 3) ^ ((tid >> 3) & 3))) * 16; // src col bytes
    const int rslot = (kq ^ ((fr >> 1) & 3)) * 16;         // read-side slot

    i32x4 acc[8][4] = {};
    i32x4 av0[4], av1[4], bv0[2], bv1[2];

    // stage one A half-tile (h: rows with bit6==h) of K-chunk kt into buf
    auto stageA = [&](int kt, int buf, int h) {
        const int grow = row0 + (sw >> 6) * 128 + h * 64 + (sw & 63);
        const signed char* src = Xq + (size_t)grow * FDIM + kt * BKB + sce;
        char* dst = lds + buf * DBUF_BYTES + h * HT_BYTES + wave * 1024;
        __builtin_amdgcn_global_load_lds((const AS1 void*)src,
                                         (AS3 void*)dst, 16, 0, 0);
    };
    // stage one B half-tile (h: rows with bit5==h)
    auto stageB = [&](int kt, int buf, int h) {
        const int grow = col0 + (sw >> 5) * 64 + h * 32 + (sw & 31);
        const signed char* src = Mq + (size_t)grow * FDIM + kt * BKB + sce;
        char* dst = lds + buf * DBUF_BYTES + 16384 + h * HT_BYTES + wave * 1024;
        __builtin_amdgcn_global_load_lds((const AS1 void*)src,
                                         (AS3 void*)dst, 16, 0, 0);
    };

    auto loadA = [&](int buf, int mh, i32x4 (&dst)[4]) {
        const char* base = lds + buf * DBUF_BYTES + mh * HT_BYTES;
#pragma unroll
        for (int f = 0; f < 4; ++f) {
            const int w = wr * 64 + f * 16 + fr;
            dst[f] = *(const i32x4*)(base + w * 64 + rslot);
        }
    };
    auto loadB = [&](int buf, int nh, i32x4 (&dst)[2]) {
        const char* base = lds + buf * DBUF_BYTES + 16384 + nh * HT_BYTES;
#pragma unroll
        for (int f = 0; f < 2; ++f) {
            const int w = wc * 32 + f * 16 + fr;
            dst[f] = *(const i32x4*)(base + w * 64 + rslot);
        }
    };

    // prologue: 7 half-tiles (buf0 chunk0 complete + 3/4 of buf1 chunk1)
    stageA(0, 0, 0); stageB(0, 0, 0); stageB(0, 0, 1); stageA(0, 0, 1);
    stageA(1, 1, 0); stageB(1, 1, 0); stageB(1, 1, 1);
    asm volatile("s_waitcnt vmcnt(3)" ::: "memory");   // buf0 chunk0 landed
    __builtin_amdgcn_s_barrier();
    SCHEDBAR();
    loadA(0, 0, av0); loadB(0, 0, bv0);                // frags for ph1 (t=0)
    SCHEDBAR();

    for (int t = 0; t < NI; ++t) {
        const int kO1 = 2 * t + 1;                 // odd chunk (buf1), valid
        const int kE2 = (2 * t + 2) & (NT - 1);    // next even (dummy-wraps at end)
        const int kO3 = (2 * t + 3) & (NT - 1);    // next odd

        // ph1: QUAD(A0,B0 | buf0); stage Ah1(buf1,kO1); rd bv1 <- B(buf0,nh1)
        stageA(kO1, 1, 1);
        MIDSYNC();
        loadB(0, 1, bv1);
        SCHEDBAR();
        QUAD(0, av0, bv0, 0);
        ENDBAR();

        // ph2: QUAD(A0,B1 | buf0); stage Ah0(buf0,kE2); rd av1 <- A(buf0,mh1)
        stageA(kE2, 0, 0);
        MIDSYNC();
        loadA(0, 1, av1);
        SCHEDBAR();
        QUAD(0, av0, bv1, 1);
        ENDBAR();

        // ph3: QUAD(A1,B0 | buf0); stage Bh0(buf0,kE2)
        stageB(kE2, 0, 0);
        MIDSYNC();
        QUAD(1, av1, bv0, 0);
        ENDBAR();

        // ph4: QUAD(A1,B1 | buf0); stage Bh1(buf0,kE2); vmcnt(3);
        //      rd av0,bv0 <- A(buf1,mh0),B(buf1,nh0)   [kO1, landed by vmcnt]
        stageB(kE2, 0, 1);
        asm volatile("s_waitcnt vmcnt(3)" ::: "memory");
        MIDSYNC();
        loadA(1, 0, av0); loadB(1, 0, bv0);
        SCHEDBAR();
        QUAD(1, av1, bv1, 1);
        ENDBAR();

        // ph5: QUAD(A0,B0 | buf1); stage Ah1(buf0,kE2); rd bv1 <- B(buf1,nh1)
        stageA(kE2, 0, 1);
        MIDSYNC();
        loadB(1, 1, bv1);
        SCHEDBAR();
        QUAD(0, av0, bv0, 0);
        ENDBAR();

        // ph6: QUAD(A0,B1 | buf1); stage Ah0(buf1,kO3); rd av1 <- A(buf1,mh1)
        stageA(kO3, 1, 0);
        MIDSYNC();
        loadA(1, 1, av1);
        SCHEDBAR();
        QUAD(0, av0, bv1, 1);
        ENDBAR();

        // ph7: QUAD(A1,B0 | buf1); stage Bh0(buf1,kO3)
        stageB(kO3, 1, 0);
        MIDSYNC();
        QUAD(1, av1, bv0, 0);
        ENDBAR();

        // ph8: QUAD(A1,B1 | buf1); stage Bh1(buf1,kO3); vmcnt(3);
        //      rd av0,bv0 <- A(buf0,mh0),B(buf0,nh0)   [kE2, landed by vmcnt]
        stageB(kO3, 1, 1);
        asm volatile("s_waitcnt vmcnt(3)" ::: "memory");
        MIDSYNC();
        loadA(0, 0, av0); loadB(0, 0, bv0);
        SCHEDBAR();
        QUAD(1, av1, bv1, 1);
        ENDBAR();
    }

    // drain dummy stages + dead read-aheads; sync before epilogue reuses LDS
    asm volatile("s_waitcnt vmcnt(0) lgkmcnt(0)" ::: "memory");
    __builtin_amdgcn_s_barrier();
    SCHEDBAR();

    // ---- epilogue: per-wave LDS transpose (16-row passes) -> float4 nt stores
    // out[i][j] = TSC*acc - xsq[i] - msq[j]
    float* wtile = (float*)(lds + wave * EPI_WAVE_BYTES);  // [16][68] f32
    const int rr = lane >> 4;              // 0..3 (row within 4-row group)
    const int cq = lane & 15;              // col-quad index
    const int gc = col0 + wc * 64 + cq * 4;
    float ms0 = 0.f, ms1 = 0.f, ms2 = 0.f, ms3 = 0.f;
    if (gc < CDIM) {
        ms0 = msq[gc]; ms1 = msq[gc + 1]; ms2 = msq[gc + 2]; ms3 = msq[gc + 3];
    }

#pragma unroll
    for (int p = 0; p < 8; ++p) {          // rows [p*16, p*16+16) of 128
        // scatter one fm-subtile into the wave's [16][68] chunk
#pragma unroll
        for (int fn = 0; fn < 4; ++fn) {
            const int lr = kq * 4;
            const int lc = fn * 16 + fr;
#pragma unroll
            for (int r = 0; r < 4; ++r)
                wtile[(lr + r) * 68 + lc] = (float)acc[p][fn][r];
        }
        asm volatile("s_waitcnt lgkmcnt(0)" ::: "memory");
        SCHEDBAR();

        if (gc < CDIM) {
#pragma unroll
            for (int i = 0; i < 4; ++i) {
                const int row = i * 4 + rr;                 // [0,16)
                f32x4 v = *(const f32x4*)&wtile[row * 68 + cq * 4];
                const int gr = row0 + wr * 128 + p * 16 + row;
                const float xsv = xsq[gr];
                f32x4 o;
                o[0] = TSC * v[0] - xsv - ms0;
                o[1] = TSC * v[1] - xsv - ms1;
                o[2] = TSC * v[2] - xsv - ms2;
                o[3] = TSC * v[3] - xsv - ms3;
                __builtin_nontemporal_store(
                    o, (f32x4*)(out + (size_t)gr * CDIM + gc));
            }
        }
        // wave-local reuse of wtile in next pass: ensure reads retired
        asm volatile("s_waitcnt lgkmcnt(0)" ::: "memory");
        SCHEDBAR();
    }
}

// ---------------------------------------------------------------------------
extern "C" void kernel_launch(void* const* d_in, const int* in_sizes, int n_in,
                              void* d_out, int out_size, void* d_ws, size_t ws_size,
                              hipStream_t stream) {
    const float* x     = (const float*)d_in[0];   // [8192, 2048]
    const float* means = (const float*)d_in[1];   // [10000, 2048]
    float* out = (float*)d_out;                   // [8192, 10000]

    char* ws = (char*)d_ws;
    signed char* Xq = (signed char*)ws;                            // 8192*2048 i8
    signed char* Mq = (signed char*)(ws + (size_t)BDIM * FDIM);    // 10240*2048 i8
    float* xsq = (float*)(ws + (size_t)BDIM * FDIM + (size_t)CPAD * FDIM);
    float* msq = xsq + BDIM;

    (void)hipFuncSetAttribute((const void*)nscm_gemm,
                              hipFuncAttributeMaxDynamicSharedMemorySize,
                              LDS_BYTES);

    convert_rows<<<BDIM + CPAD, 256, 0, stream>>>(x, means, Xq, Mq, xsq, msq);

    nscm_gemm<<<NWG, 512, LDS_BYTES, stream>>>(Xq, Mq, xsq, msq, out);
}